// Round 5
// baseline (57.790 us; speedup 1.0000x reference)
//
#include <hip/hip_runtime.h>

#define N 256
#define NN 65536

typedef __attribute__((ext_vector_type(8))) __bf16 bf16x8;
typedef __attribute__((ext_vector_type(4))) __bf16 bf16x4v;
typedef __attribute__((ext_vector_type(4))) float f32x4;

// ---- workspace layout (float offsets) ----
#define F_PART   0u         // [256 blocks][256 b][32 ml] yadj partials
#define F_SPART  2097152u   // [8 mt][256 b][256 n] s_adj partials
#define F_WSC    2621440u   // [256] colsum(W)+strided colsum(cl_bias)
#define F_SFULL  2621696u   // [65536]
#define F_YADJ   2687232u   // [65536]
#define WS_FLOATS 2752768u

static __device__ __forceinline__ f32x4 mfma16(bf16x8 a, bf16x8 b, f32x4 c) {
  return __builtin_amdgcn_mfma_f32_16x16x32_bf16(a, b, c, 0, 0, 0);
}
static __device__ __forceinline__ bf16x4v pack4(float4 v) {
  bf16x4v r;
  r[0] = (__bf16)v.x; r[1] = (__bf16)v.y; r[2] = (__bf16)v.z; r[3] = (__bf16)v.w;
  return r;
}
static __device__ __forceinline__ bf16x8 pack8(float4 a, float4 b) {
  bf16x8 r;
  r[0] = (__bf16)a.x; r[1] = (__bf16)a.y; r[2] = (__bf16)a.z; r[3] = (__bf16)a.w;
  r[4] = (__bf16)b.x; r[5] = (__bf16)b.y; r[6] = (__bf16)b.z; r[7] = (__bf16)b.w;
  return r;
}

#define BAR()                                                  \
  asm volatile("s_waitcnt lgkmcnt(0)" ::: "memory");           \
  __builtin_amdgcn_s_barrier();                                \
  __builtin_amdgcn_sched_barrier(0);

// ============================================================================
// kbig v4b: grid 256 = 8 mt x 32 s; 512 thr (8 waves x 32 b-rows).
//   ALL 8 clw n-tiles issued to VGPRs up front (128KB/block in flight),
//   then 2 phases of {LDS-write 4 tiles -> barrier -> compute 4 tiles}.
//   Runtime bounded by stream(256KB/CU) + compute tail regardless of
//   waitcnt policy. v4 bug fixed: wsc 'red' buffer (8KB) reuses the xl
//   region instead of overflowing the LDS allocation.
// LDS: 8 tiles x 16KB @0 | xl[8][256]f32 @131072 (red reuses this) |
//      sred[8][256]f32 @139264   (total 147456 B -> 1 block/CU)
// ============================================================================
__global__ void __launch_bounds__(512, 2) kbig(
    const float* __restrict__ X, const float* __restrict__ ctx,
    const float* __restrict__ W, const float* __restrict__ clb,
    const float* __restrict__ clw, float* __restrict__ ws)
{
  extern __shared__ char smem[];
  float* xl   = (float*)(smem + 131072);
  float* sred = (float*)(smem + 139264);
  float* red  = (float*)(smem + 131072);  // reuses xl post-loop (8KB, fits)
  const int t = threadIdx.x;
  const int mt = blockIdx.x >> 5, s = blockIdx.x & 31;
  const int n0 = s * 8, m0g = mt * 32;
  const float4* clwf4 = (const float4*)clw;

  int gm[4], gk[4];
#pragma unroll
  for (int i = 0; i < 4; ++i) {
    const int idx = i * 512 + t;
    gm[i] = idx >> 6; gk[i] = idx & 63;
  }

  float4 g0[4], g1[4], g2[4], g3[4], g4[4], g5[4], g6[4], g7[4];
#define ISSUE(TT, G)                                                        \
  _Pragma("unroll")                                                         \
  for (int i = 0; i < 4; ++i)                                               \
    G[i] = clwf4[(m0g + gm[i]) * 16384 + (n0 + (TT)) * 64 + gk[i]];
#define WRITE(TT, G)                                                        \
  _Pragma("unroll")                                                         \
  for (int i = 0; i < 4; ++i)                                               \
    *(bf16x4v*)(smem + (TT) * 16384 + gm[i] * 512 +                         \
                ((gk[i] * 8) ^ ((gm[i] & 7) << 4))) = pack4(G[i]);

  // issue the entire clw stream first (HBM-bound bulk)
  ISSUE(0, g0) ISSUE(1, g1) ISSUE(2, g2) ISSUE(3, g3)
  ISSUE(4, g4) ISSUE(5, g5) ISSUE(6, g6) ISSUE(7, g7)

  // X slab: xl[nn][b] = X[b, n0+nn]
  if (t < 256) {
    const float4* xp = (const float4*)(X + t * N + n0);
    const float4 x0 = xp[0], x1 = xp[1];
    xl[0 * 256 + t] = x0.x; xl[1 * 256 + t] = x0.y;
    xl[2 * 256 + t] = x0.z; xl[3 * 256 + t] = x0.w;
    xl[4 * 256 + t] = x1.x; xl[5 * 256 + t] = x1.y;
    xl[6 * 256 + t] = x1.z; xl[7 * 256 + t] = x1.w;
  }

  const int lane = t & 63, w = t >> 6;
  const int wb = w * 32, l15 = lane & 15, lhi = lane >> 4;
  const int swz = (l15 & 7) << 4;

  // hoisted ctx A-frags (loop-invariant; ctx is L2-resident)
  bf16x8 af[2][8];
#pragma unroll
  for (int i = 0; i < 2; ++i)
#pragma unroll
    for (int c = 0; c < 8; ++c) {
      const float4* p =
          (const float4*)(ctx + (wb + i * 16 + l15) * N + c * 32 + lhi * 8);
      af[i][c] = pack8(p[0], p[1]);
    }

  const f32x4 zero = {0.f, 0.f, 0.f, 0.f};
  f32x4 acc[2][2];
  acc[0][0] = zero; acc[0][1] = zero; acc[1][0] = zero; acc[1][1] = zero;

#define COMP(NNV)                                                           \
  {                                                                         \
    char* buf = smem + (NNV) * 16384;                                       \
    f32x4 h[2][2];                                                          \
    h[0][0] = zero; h[0][1] = zero; h[1][0] = zero; h[1][1] = zero;         \
    _Pragma("unroll")                                                       \
    for (int c = 0; c < 8; ++c) {                                           \
      const int kb = c * 64 + lhi * 16;                                     \
      bf16x8 b0 = *(const bf16x8*)(buf + l15 * 512 + (kb ^ swz));           \
      bf16x8 b1 = *(const bf16x8*)(buf + (16 + l15) * 512 + (kb ^ swz));    \
      h[0][0] = mfma16(af[0][c], b0, h[0][0]);                              \
      h[0][1] = mfma16(af[0][c], b1, h[0][1]);                              \
      h[1][0] = mfma16(af[1][c], b0, h[1][0]);                              \
      h[1][1] = mfma16(af[1][c], b1, h[1][1]);                              \
    }                                                                       \
    _Pragma("unroll")                                                       \
    for (int fb = 0; fb < 2; ++fb) {                                        \
      _Pragma("unroll")                                                     \
      for (int r = 0; r < 4; ++r) {                                         \
        const int brow = wb + fb * 16 + lhi * 4 + r;                        \
        const float xv = xl[(NNV) * 256 + brow];                            \
        acc[fb][0][r] += xv * h[fb][0][r];                                  \
        acc[fb][1][r] += xv * h[fb][1][r];                                  \
        float v = h[fb][0][r] + h[fb][1][r];                                \
        v += __shfl_xor(v, 1); v += __shfl_xor(v, 2);                       \
        v += __shfl_xor(v, 4); v += __shfl_xor(v, 8);                       \
        if (l15 == 0) sred[(NNV) * 256 + brow] = v;                         \
      }                                                                     \
    }                                                                       \
  }

  // phase 1: stage tiles 0-3, compute them (tiles 4-7 still in flight)
  WRITE(0, g0) WRITE(1, g1) WRITE(2, g2) WRITE(3, g3)
  BAR();
  COMP(0) COMP(1) COMP(2) COMP(3)
  // phase 2: stage tiles 4-7 (long since landed), compute
  WRITE(4, g4) WRITE(5, g5) WRITE(6, g6) WRITE(7, g7)
  BAR();
  COMP(4) COMP(5) COMP(6) COMP(7)
#undef ISSUE
#undef WRITE
#undef COMP

  // yadj partials: [block][b][32 ml] (coalesced)
  const int base = blockIdx.x * 8192;
#pragma unroll
  for (int fb = 0; fb < 2; ++fb)
#pragma unroll
    for (int fm = 0; fm < 2; ++fm)
#pragma unroll
      for (int r = 0; r < 4; ++r)
        ws[F_PART + base + (wb + fb * 16 + lhi * 4 + r) * 32 + fm * 16 + l15] =
            acc[fb][fm][r];

  // s_adj partials from sred (same-wave data): float4 of 4 n per lane
  {
    const int b = wb + (lane >> 1);
    const int nh = (lane & 1) * 4;
    float4 v;
    v.x = sred[(nh + 0) * 256 + b];
    v.y = sred[(nh + 1) * 256 + b];
    v.z = sred[(nh + 2) * 256 + b];
    v.w = sred[(nh + 3) * 256 + b];
    *(float4*)(ws + F_SPART + mt * NN + b * N + n0 + nh) = v;
  }

  // wsc: colsum of W+CB for 8 j-columns, by mt==0 blocks (red reuses xl)
  if (mt == 0) {
    __syncthreads();
    if (t < 256) {
      const float4* wp = (const float4*)(W + t * N + s * 8);
      const float4* cp = (const float4*)(clb + t * N + s * 8);
      const float4 a0 = wp[0], a1 = wp[1], b0 = cp[0], b1 = cp[1];
      red[0 * 256 + t] = a0.x + b0.x; red[1 * 256 + t] = a0.y + b0.y;
      red[2 * 256 + t] = a0.z + b0.z; red[3 * 256 + t] = a0.w + b0.w;
      red[4 * 256 + t] = a1.x + b1.x; red[5 * 256 + t] = a1.y + b1.y;
      red[6 * 256 + t] = a1.z + b1.z; red[7 * 256 + t] = a1.w + b1.w;
    }
    __syncthreads();
    if (t < 64) {
      const int jj = t >> 3, seg = t & 7;
      float v = 0.f;
#pragma unroll
      for (int i = 0; i < 32; ++i) v += red[jj * 256 + seg * 32 + i];
      v += __shfl_xor(v, 1);
      v += __shfl_xor(v, 2);
      v += __shfl_xor(v, 4);
      if (seg == 0) ws[F_WSC + s * 8 + jj] = v;
    }
  }
}

// ============================================================================
// kred: yadj = sum_s partials; s_full = wsc + sum_mt spart
// ============================================================================
__global__ void __launch_bounds__(256) kred(float* __restrict__ ws)
{
  const int o = blockIdx.x * 256 + threadIdx.x;
  const int b = o >> 8, col = o & 255;
  const int mt = col >> 5, ml = col & 31;
  float y = 0.f;
#pragma unroll
  for (int si = 0; si < 32; ++si)
    y += ws[F_PART + ((mt * 32 + si) * 256 + b) * 32 + ml];
  ws[F_YADJ + o] = y;
  float sv = ws[F_WSC + col];
#pragma unroll
  for (int q = 0; q < 8; ++q)
    sv += ws[F_SPART + q * NN + o];
  ws[F_SFULL + o] = sv;
}

// ============================================================================
// kfin: 64 blocks (32b x 32k tiles), 256 thr (4 waves, one 16x16 quadrant each)
//   d = s_full @ A  and  wx = X @ (W+CB)^T   (two fused K=256 MFMA chains)
//   out = scale*(X*d - wx - yadj);  out2 = ctx*t/(t+1) + X/(t+1)
// LDS: S@0 | XT@16384 | AT@32768 | WCB@49152 (16KB each)
// ============================================================================
__global__ void __launch_bounds__(256) kfin(
    const float* __restrict__ X, const float* __restrict__ ctx,
    const float* __restrict__ W, const float* __restrict__ clb,
    const float* __restrict__ A, const float* __restrict__ scale,
    const int* __restrict__ tptr, float* __restrict__ out,
    float* __restrict__ ws)
{
  extern __shared__ char smem[];
  const int t = threadIdx.x, blk = blockIdx.x;
  const int b0 = (blk >> 3) * 32, k0 = (blk & 7) * 32;
  {
    const int row = t >> 3, q = t & 7;
    const int sw = (row & 7) << 4;
    const float4* sp = (const float4*)(ws + F_SFULL + (b0 + row) * N);
    const float4* xp = (const float4*)(X + (b0 + row) * N);
    const float4* wp = (const float4*)(W + (k0 + row) * N);
    const float4* cp = (const float4*)(clb + (k0 + row) * N);
#pragma unroll
    for (int i = 0; i < 8; ++i) {
      const int f4 = q * 8 + i;
      const int off = row * 512 + ((f4 * 8) ^ sw);
      *(bf16x4v*)(smem + off) = pack4(sp[f4]);
      *(bf16x4v*)(smem + 16384 + off) = pack4(xp[f4]);
      const float4 wv = wp[f4], cv = cp[f4];
      float4 s2;
      s2.x = wv.x + cv.x; s2.y = wv.y + cv.y;
      s2.z = wv.z + cv.z; s2.w = wv.w + cv.w;
      *(bf16x4v*)(smem + 49152 + off) = pack4(s2);
    }
    // AT[kk][j] = A[j][k0+kk]
    const float4* ap = (const float4*)(A + t * N + k0);
    char* at = smem + 32768;
#pragma unroll
    for (int i = 0; i < 8; ++i) {
      const float4 v = ap[i];
      const int kk = i * 4;
      *(__bf16*)(at + (kk + 0) * 512 + ((t * 2) ^ (((kk + 0) & 7) << 4))) = (__bf16)v.x;
      *(__bf16*)(at + (kk + 1) * 512 + ((t * 2) ^ (((kk + 1) & 7) << 4))) = (__bf16)v.y;
      *(__bf16*)(at + (kk + 2) * 512 + ((t * 2) ^ (((kk + 2) & 7) << 4))) = (__bf16)v.z;
      *(__bf16*)(at + (kk + 3) * 512 + ((t * 2) ^ (((kk + 3) & 7) << 4))) = (__bf16)v.w;
    }
  }
  __syncthreads();
  const int lane = t & 63, w = t >> 6;
  const int l15 = lane & 15, lhi = lane >> 4;
  const int wqb = (w >> 1) * 16, wqk = (w & 1) * 16;
  const int swz = (l15 & 7) << 4;
  f32x4 accd = {0.f, 0.f, 0.f, 0.f}, accw = {0.f, 0.f, 0.f, 0.f};
#pragma unroll
  for (int c = 0; c < 8; ++c) {
    const int kb = c * 64 + lhi * 16;
    bf16x8 as  = *(const bf16x8*)(smem + (wqb + l15) * 512 + (kb ^ swz));
    bf16x8 aat = *(const bf16x8*)(smem + 32768 + (wqk + l15) * 512 + (kb ^ swz));
    bf16x8 ax  = *(const bf16x8*)(smem + 16384 + (wqb + l15) * 512 + (kb ^ swz));
    bf16x8 awc = *(const bf16x8*)(smem + 49152 + (wqk + l15) * 512 + (kb ^ swz));
    accd = mfma16(as, aat, accd);
    accw = mfma16(ax, awc, accw);
  }
  const float sc = scale[0];
  const float tf = (float)(*tptr);
  const float c1 = tf / (tf + 1.f), c2 = 1.f / (tf + 1.f);
#pragma unroll
  for (int r = 0; r < 4; ++r) {
    const int b = b0 + wqb + lhi * 4 + r, k = k0 + wqk + l15;
    const int idx = b * N + k;
    const float xv = X[idx];
    out[idx] = sc * (xv * accd[r] - accw[r] - ws[F_YADJ + idx]);
    out[NN + idx] = ctx[idx] * c1 + xv * c2;
  }
}

extern "C" void kernel_launch(void* const* d_in, const int* in_sizes, int n_in,
                              void* d_out, int out_size, void* d_ws, size_t ws_size,
                              hipStream_t stream)
{
  (void)in_sizes; (void)n_in; (void)out_size;
  const float* X     = (const float*)d_in[0];
  const float* ctx   = (const float*)d_in[1];
  const float* W     = (const float*)d_in[2];
  const float* scale = (const float*)d_in[3];
  const float* A     = (const float*)d_in[4];
  const float* clw   = (const float*)d_in[5];
  const float* clb   = (const float*)d_in[6];
  const int*   tptr  = (const int*)d_in[7];
  float* out = (float*)d_out;
  float* ws  = (float*)d_ws;

  if (ws_size < (size_t)WS_FLOATS * sizeof(float)) return;

  (void)hipFuncSetAttribute((const void*)kbig,
                            hipFuncAttributeMaxDynamicSharedMemorySize, 147456);
  (void)hipFuncSetAttribute((const void*)kfin,
                            hipFuncAttributeMaxDynamicSharedMemorySize, 65536);

  kbig<<<256, 512, 147456, stream>>>(X, ctx, W, clb, clw, ws);
  kred<<<256, 256, 0, stream>>>(ws);
  kfin<<<64, 256, 65536, stream>>>(X, ctx, W, clb, A, scale, tptr, out, ws);
}